// Round 7
// baseline (246.502 us; speedup 1.0000x reference)
//
#include <hip/hip_runtime.h>

typedef __bf16 bf16x8 __attribute__((ext_vector_type(8)));
typedef float f32x4 __attribute__((ext_vector_type(4)));

#define HW 9216
#define CCH 256

__device__ __forceinline__ unsigned short f2bf(float f) {
  unsigned u = __float_as_uint(f);
  unsigned r = (u + 0x7FFFu + ((u >> 16) & 1u)) >> 16;
  return (unsigned short)r;
}
__device__ __forceinline__ float bf2f(unsigned short h) {
  return __uint_as_float(((unsigned)h) << 16);
}

// async 16B/lane global->LDS DMA; LDS dst = wave-uniform base, lane writes base+lane*16
__device__ __forceinline__ void async16(const unsigned short* g, unsigned short* l) {
  __builtin_amdgcn_global_load_lds(
      (const __attribute__((address_space(1))) unsigned int*)g,
      (__attribute__((address_space(3))) unsigned int*)l, 16, 0, 0);
}

// y[0..8) += gk * unpack_bf16x8(v)
__device__ __forceinline__ void fma8(float* y, float gk, uint4 v) {
  const unsigned* u = (const unsigned*)&v;
#pragma unroll
  for (int i = 0; i < 4; ++i) {
    y[2 * i] += gk * __uint_as_float(u[i] << 16);
    y[2 * i + 1] += gk * __uint_as_float(u[i] & 0xFFFF0000u);
  }
}

// ---------- x [n][ci][p] fp32 -> xb [n*9216+p][ci] bf16 ----------
__global__ __launch_bounds__(256) void xpose(const float* __restrict__ x,
                                             unsigned short* __restrict__ xb) {
  __shared__ float tile[64][65];
  int t = threadIdx.x;
  int p0 = blockIdx.x * 64, ci0 = blockIdx.y * 64, n = blockIdx.z;
  int cl = t & 63, q = t >> 6;
#pragma unroll
  for (int i = 0; i < 16; ++i) {
    int cir = q + i * 4;
    tile[cir][cl] = x[((size_t)(n * 256 + ci0 + cir)) * HW + p0 + cl];
  }
  __syncthreads();
#pragma unroll
  for (int i = 0; i < 16; ++i) {
    int pr = q + i * 4;
    xb[((size_t)(n * HW + p0 + pr)) * 256 + ci0 + cl] = f2bf(tile[cl][pr]);
  }
}

// ---------- weight repack ----------
__global__ __launch_bounds__(256) void prep_w(const float* __restrict__ Ws,
                                              const float* __restrict__ Wc,
                                              unsigned short* __restrict__ Wsb,
                                              unsigned short* __restrict__ Wcb) {
  int u = blockIdx.x * 256 + threadIdx.x;
  if (u < 393216) {
    int j = u >> 8, k = u & 255;
    int co = j & 255, b = j >> 8;
    Wsb[u] = f2bf(Ws[(size_t)co * 1536 + b * 256 + k]);
  } else {
    int v = u - 393216;
    if (v < 110592) {
      int co = v / 2304, r = v % 2304;
      int j = r >> 8, ci = r & 255;
      Wcb[v] = (co < 45) ? f2bf(Wc[(size_t)co * 2304 + ci * 9 + j]) : (unsigned short)0;
    }
  }
}

// ---------- gemm_z: all 1536 cols in one launch, async-LDS staged ----------
// LDS layout = DMA lane order: chunk c covers rows c*16..c*16+15; lane l ->
// row c*16 + (l>>2), kq = l&3. uint4 idx = c*64 + l. Element (mm,kq) at
// uint4 idx (mm>>4)*64 + (mm&15)*4 + kq.
__global__ __launch_bounds__(256) void gemm_z(const unsigned short* __restrict__ xb,
                                              const unsigned short* __restrict__ Wsb,
                                              unsigned short* __restrict__ z) {
  __shared__ unsigned short As[4096];  // 128 rows x 32 k
  __shared__ unsigned short Bs[4096];
  int t = threadIdx.x;
  int wid = t >> 6, lane = t & 63;
  int m0 = blockIdx.x * 128, c0 = blockIdx.y * 128;
  int wm = (wid >> 1) * 64, wn = (wid & 1) * 64;
  int q = lane >> 4, ln = lane & 15;
  int lr = lane >> 2, lkq = lane & 3;
  f32x4 acc[4][4] = {};

  for (int k0 = 0; k0 < 256; k0 += 32) {
#pragma unroll
    for (int r = 0; r < 2; ++r) {
      int c = wid + r * 4;
      async16(xb + (size_t)(m0 + c * 16 + lr) * 256 + k0 + lkq * 8, &As[c * 512]);
      async16(Wsb + (size_t)(c0 + c * 16 + lr) * 256 + k0 + lkq * 8, &Bs[c * 512]);
    }
    __syncthreads();
    bf16x8 a[4], b[4];
#pragma unroll
    for (int f = 0; f < 4; ++f) {
      a[f] = ((const bf16x8*)As)[((wm >> 4) + f) * 64 + ln * 4 + q];
      b[f] = ((const bf16x8*)Bs)[((wn >> 4) + f) * 64 + ln * 4 + q];
    }
#pragma unroll
    for (int fm = 0; fm < 4; ++fm)
#pragma unroll
      for (int fn = 0; fn < 4; ++fn)
        acc[fm][fn] = __builtin_amdgcn_mfma_f32_16x16x32_bf16(a[fm], b[fn], acc[fm][fn], 0, 0, 0);
    __syncthreads();
  }

  int sl = c0 >> 8;
  int cb = c0 & 255;
#pragma unroll
  for (int fm = 0; fm < 4; ++fm) {
    int mrow = m0 + wm + fm * 16 + q * 4;
#pragma unroll
    for (int fn = 0; fn < 4; ++fn) {
      int cc = cb + wn + fn * 16 + ln;
#pragma unroll
      for (int r = 0; r < 4; ++r)
        z[((size_t)sl * 18432 + mrow + r) * 256 + cc] = f2bf(acc[fm][fn][r]);
    }
  }
}

// ---------- guidance GEMM ----------
__global__ __launch_bounds__(256) void gemm_g(const unsigned short* __restrict__ xb,
                                              const unsigned short* __restrict__ Wcb,
                                              float* __restrict__ g45) {
  __shared__ unsigned short As[4 * 64 * 8];
  __shared__ unsigned short Bs[4 * 48 * 8];
  int t = threadIdx.x;
  int m0 = blockIdx.x * 64;
  int wid = t >> 6, lane = t & 63;
  int q = lane >> 4, ln = lane & 15;
  int mm = t >> 2, kq = t & 3;
  int m = m0 + mm;
  int nimg = m / HW, p = m % HW;
  int h = p / 96, w = p % 96;
  int mbase = nimg * HW;
  f32x4 acc[3] = {};

  for (int k0 = 0; k0 < 2304; k0 += 32) {
    int j = k0 >> 8;
    int dy = j / 3 - 1, dx = j % 3 - 1;
    int hh = h + dy, ww = w + dx;
    uint4 av = make_uint4(0, 0, 0, 0);
    if ((unsigned)hh < 96u && (unsigned)ww < 96u)
      av = *(const uint4*)(xb + (size_t)(mbase + hh * 96 + ww) * 256 + (k0 & 255) + kq * 8);
    ((uint4*)As)[kq * 64 + mm] = av;
    if (t < 192) {
      int nn = t >> 2, kq2 = t & 3;
      ((uint4*)Bs)[kq2 * 48 + nn] = *(const uint4*)(Wcb + (size_t)nn * 2304 + k0 + kq2 * 8);
    }
    __syncthreads();
    bf16x8 a = ((const bf16x8*)As)[q * 64 + wid * 16 + ln];
#pragma unroll
    for (int fn = 0; fn < 3; ++fn) {
      bf16x8 b = ((const bf16x8*)Bs)[q * 48 + fn * 16 + ln];
      acc[fn] = __builtin_amdgcn_mfma_f32_16x16x32_bf16(a, b, acc[fn], 0, 0, 0);
    }
    __syncthreads();
  }
#pragma unroll
  for (int fn = 0; fn < 3; ++fn) {
    int col = fn * 16 + ln;
    int mrow = m0 + wid * 16 + q * 4;
#pragma unroll
    for (int r = 0; r < 4; ++r)
      g45[(size_t)(mrow + r) * 48 + col] = acc[fn][r];
  }
}

// ---------- softmax -> bf16 col-major gsmb[col][img][p] ----------
__global__ __launch_bounds__(256) void softmax45(const float* __restrict__ g45,
                                                 unsigned short* __restrict__ gsmb) {
  int m = blockIdx.x * 256 + threadIdx.x;
  int img = m / HW, p = m % HW;
  const float* g = g45 + (size_t)m * 48;
  for (int grp = 0; grp < 5; ++grp) {
    float v[9], mx = -1e30f;
#pragma unroll
    for (int k = 0; k < 9; ++k) { v[k] = g[grp * 9 + k]; mx = fmaxf(mx, v[k]); }
    float s = 0.f;
#pragma unroll
    for (int k = 0; k < 9; ++k) { v[k] = __expf(v[k] - mx); s += v[k]; }
    float inv = 1.f / s;
#pragma unroll
    for (int k = 0; k < 9; ++k) {
      int col = grp * 9 + k;
      gsmb[((size_t)(col * 2 + img)) * HW + p] = f2bf(v[k] * inv);
    }
  }
}

// ---------- accum: single pass, all 6 slices; block = (row h, img, 16-ch group) ----------
// 192 threads = 96 px x 2 ch-chunks(8). 16 staged z-rows (48KB) + 45 weight rows
// (8.4KB) = 57.8KB static LDS -> 2 blocks/CU. All staging via async DMA.
__constant__ const int SLs[16] = {0, 1,1,1, 2,2,2, 3,3,3, 4,4,4, 5,5,5};
__constant__ const int DYs[16] = {0, -1,0,1, -6,0,6, -12,0,12, -24,0,24, -36,0,36};

__global__ __launch_bounds__(192) void accum_all(const unsigned short* __restrict__ z,
                                                 const unsigned short* __restrict__ gsmb,
                                                 float* __restrict__ yacc,
                                                 float* __restrict__ stats) {
  __shared__ unsigned short rows[16 * 96 * 16];  // [slot][px][16ch]
  __shared__ unsigned short gw[45 * 96];         // [col][px]
  int t = threadIdx.x;
  int h = blockIdx.x, img = blockIdx.y, cg = blockIdx.z;
  int wid = t >> 6, lane = t & 63;

  // stage z rows: slot s, chunk wid covers px wid*32..+32
#pragma unroll
  for (int s = 0; s < 16; ++s) {
    int hr = min(max(h + DYs[s], 0), 95);
    const unsigned short* src =
        z + ((size_t)(SLs[s] * 18432 + img * HW + hr * 96)) * 256 + cg * 16;
    async16(src + (size_t)(wid * 32 + (lane >> 1)) * 256 + (lane & 1) * 8,
            &rows[(s * 96 + wid * 32) * 16]);
  }
  // stage weight rows (192B each = 12 lanes)
  for (int c = wid; c < 45; c += 3) {
    const unsigned short* src = gsmb + ((size_t)(c * 2 + img)) * HW + h * 96;
    if (lane < 12) async16(src + lane * 8, &gw[c * 96]);
  }
  __syncthreads();

  int c8 = t & 1, px = t >> 1;
  bool rv[16];
#pragma unroll
  for (int s = 0; s < 16; ++s) rv[s] = (unsigned)(h + DYs[s]) < 96u;

  float y[8];
#pragma unroll
  for (int j = 0; j < 8; ++j) y[j] = 0.f;
  fma8(y, 1.f, *(const uint4*)&rows[px * 16 + c8 * 8]);  // identity (slot 0)

  const int dil[6] = {0, 1, 6, 12, 24, 36};
#pragma unroll
  for (int b = 1; b <= 5; ++b) {
    const int d = dil[b];
    const int sb = 1 + (b - 1) * 3;
#pragma unroll
    for (int k = 0; k < 9; ++k) {
      const int slot = sb + k / 3;
      const int dx = (k % 3 - 1) * d;
      int wt = px + dx;
      bool valid = rv[slot] && ((unsigned)wt < 96u);
      int widx = valid ? wt : px;
      float gk = valid ? bf2f(gw[((b - 1) * 9 + k) * 96 + px]) : 0.f;
      fma8(y, gk, *(const uint4*)&rows[(slot * 96 + widx) * 16 + c8 * 8]);
    }
  }

  size_t ybase = ((size_t)img * HW + h * 96 + px) * 256 + cg * 16 + c8 * 8;
  *(float4*)(yacc + ybase) = make_float4(y[0], y[1], y[2], y[3]);
  *(float4*)(yacc + ybase + 4) = make_float4(y[4], y[5], y[6], y[7]);

  // BN stats: shfl over px within wave (bit0=c8 preserved), LDS across 3 waves
  float s1[8], s2[8];
#pragma unroll
  for (int j = 0; j < 8; ++j) { s1[j] = y[j]; s2[j] = y[j] * y[j]; }
#pragma unroll
  for (int off = 2; off <= 32; off <<= 1) {
#pragma unroll
    for (int j = 0; j < 8; ++j) {
      s1[j] += __shfl_xor(s1[j], off);
      s2[j] += __shfl_xor(s2[j], off);
    }
  }
  __syncthreads();  // gw reads complete before aliasing
  float* red = (float*)gw;  // [2 stats][3 waves x 2 c8][8]
  if (lane < 2) {
#pragma unroll
    for (int j = 0; j < 8; ++j) {
      red[(wid * 2 + lane) * 8 + j] = s1[j];
      red[48 + (wid * 2 + lane) * 8 + j] = s2[j];
    }
  }
  __syncthreads();
  if (t < 32) {
    int ch = t & 15, st = t >> 4;
    int c8i = ch >> 3, j = ch & 7;
    float a = 0.f;
#pragma unroll
    for (int w2 = 0; w2 < 3; ++w2) a += red[st * 48 + (w2 * 2 + c8i) * 8 + j];
    atomicAdd(&stats[st * 256 + cg * 16 + ch], a);
  }
}

// ---------- normalize + affine + transpose ----------
__global__ __launch_bounds__(256) void bn_apply(const float* __restrict__ yacc,
                                                const float* __restrict__ stats,
                                                const float* __restrict__ gamma,
                                                const float* __restrict__ beta,
                                                float* __restrict__ out) {
  __shared__ float tile[64][65];
  int t = threadIdx.x;
  int p0 = blockIdx.x * 64, co0 = blockIdx.y * 64, n = blockIdx.z;
  int cl = t & 63, q = t >> 6;
#pragma unroll
  for (int i = 0; i < 16; ++i) {
    int pr = q + i * 4;
    tile[pr][cl] = yacc[((size_t)n * HW + p0 + pr) * 256 + co0 + cl];
  }
  __syncthreads();
  const float inv_cnt = 1.f / 18432.f;
#pragma unroll
  for (int i = 0; i < 16; ++i) {
    int cr = q + i * 4;
    int c = co0 + cr;
    float mean = stats[c] * inv_cnt;
    float var = stats[256 + c] * inv_cnt - mean * mean;
    float sc = rsqrtf(var + 1e-5f) * gamma[c];
    float sh = beta[c] - mean * sc;
    out[(size_t)(n * 256 + c) * HW + p0 + cl] = tile[cl][cr] * sc + sh;
  }
}

extern "C" void kernel_launch(void* const* d_in, const int* in_sizes, int n_in,
                              void* d_out, int out_size, void* d_ws, size_t ws_size,
                              hipStream_t stream) {
  const float* x = (const float*)d_in[0];
  const float* Wc = (const float*)d_in[1];
  const float* Ws = (const float*)d_in[2];
  const float* gamma = (const float*)d_in[3];
  const float* beta = (const float*)d_in[4];
  float* out = (float*)d_out;

  unsigned short* xb = (unsigned short*)d_ws;   // 4718592 us
  unsigned short* Wsb = xb + 4718592;           // 393216 us
  unsigned short* Wcb = Wsb + 393216;           // 110592 us
  unsigned short* z = Wcb + 110592;             // 28311552 us  [6 slices][18432][256]
  unsigned short* gsmb = z + 28311552;          // 829440 us    [45][2][9216]
  float* g45 = (float*)(gsmb + 829440);         // 884736 f32
  float* yacc = g45 + 884736;                   // 4718592 f32
  float* stats = yacc + 4718592;                // 512 f32   (total ~91 MB)

  hipMemsetAsync(stats, 0, 512 * sizeof(float), stream);
  xpose<<<dim3(144, 4, 2), 256, 0, stream>>>(x, xb);
  prep_w<<<1968, 256, 0, stream>>>(Ws, Wc, Wsb, Wcb);
  gemm_g<<<288, 256, 0, stream>>>(xb, Wcb, g45);
  softmax45<<<72, 256, 0, stream>>>(g45, gsmb);

  gemm_z<<<dim3(144, 12), 256, 0, stream>>>(xb, Wsb, z);
  accum_all<<<dim3(96, 2, 16), 192, 0, stream>>>(z, gsmb, yacc, stats);

  bn_apply<<<dim3(144, 4, 2), 256, 0, stream>>>(yacc, stats, gamma, beta, out);
}